// Round 2
// baseline (99.166 us; speedup 1.0000x reference)
//
#include <hip/hip_runtime.h>
#include <hip/hip_bf16.h>

#define CCH 256      // channels
#define HH 128
#define WW 128
#define SS (HH*WW)   // 16384 pixels per batch
#define NB 8         // batch
#define NK 19        // keypoints
#define STILE 64     // pixels per block

typedef __attribute__((ext_vector_type(8))) short short8v;   // 8 bf16 = 4 VGPR (MFMA operand)
typedef __attribute__((ext_vector_type(4))) float f32x4;     // MFMA accum

static __device__ __forceinline__ unsigned short f2bf(float x) {
    __hip_bfloat16 h = __float2bfloat16(x);
    return *reinterpret_cast<unsigned short*>(&h);
}
static __device__ __forceinline__ float tanh_fast(float x) {
    // 1 - 2/(e^{2x}+1): monotone, no inf-inf, exact +/-1 saturation
    float e = __expf(2.f * x);
    return 1.f - 2.f / (e + 1.f);
}

// ---------------------------------------------------------------------------
// Kernel 1: precompute folded biases, delta weights, keypoint pixels, and
// img_fc_w rearranged to bf16 in MFMA A-fragment order:
//   Wfrag[((ks*16 + ot)*64 + lane)*8 + j] = bf16(W[ot*16 + (lane&15)][ks*32 + (lane>>4)*8 + j])
// ---------------------------------------------------------------------------
__global__ __launch_bounds__(256) void precompute_kernel(
    const float* __restrict__ kf,        // [B,K,3]
    const float* __restrict__ img_fc_w,  // [256,256]
    const float* __restrict__ img_fc_b,  // [256]
    const float* __restrict__ kp_proj_w, // [19,19]
    const float* __restrict__ kp_proj_b, // [19]
    const float* __restrict__ kp_fc_w,   // [256,19]
    const float* __restrict__ kp_fc_b,   // [256]
    float* __restrict__ cb,              // [256] combined bias
    float* __restrict__ delta,           // [256*19]
    int* __restrict__ pix,               // [B*K]
    unsigned short* __restrict__ Wfrag)  // [8*16*64*8]
{
    int t = threadIdx.x;
    {
        float acc = img_fc_b[t] + kp_fc_b[t];
        for (int k2 = 0; k2 < NK; ++k2) acc += kp_fc_w[t * NK + k2] * kp_proj_b[k2];
        cb[t] = acc;
        for (int k = 0; k < NK; ++k) {
            float d = 0.f;
            for (int k2 = 0; k2 < NK; ++k2) d += kp_fc_w[t * NK + k2] * kp_proj_w[k2 * NK + k];
            delta[t * NK + k] = d;
        }
    }
    if (t < NB * NK) {
        float kx = kf[t * 3 + 0], ky = kf[t * 3 + 1], vis = kf[t * 3 + 2];
        int p = -1;
        if (vis > 0.f) {
            int xi = (int)fminf(fmaxf(kx * (1.f / (float)WW), 0.f), (float)(WW - 1));
            int yi = (int)fminf(fmaxf(ky * (1.f / (float)HH), 0.f), (float)(HH - 1));
            p = yi * WW + xi;
        }
        pix[t] = p;
    }
    for (int g = t; g < 8 * 16 * 64; g += 256) {
        int lane = g & 63;
        int ot = (g >> 6) & 15;
        int ks = g >> 10;
        int o = ot * 16 + (lane & 15);
        int c0 = ks * 32 + (lane >> 4) * 8;
#pragma unroll
        for (int j = 0; j < 8; ++j)
            Wfrag[g * 8 + j] = f2bf(img_fc_w[o * CCH + c0 + j]);
    }
}

// ---------------------------------------------------------------------------
// Kernel 2: main fused GEMM + epilogue. Block = 512 thr (8 waves).
// Tile: 256 o x 64 s. Wave w owns o in [w*32, w*32+32)  (m = 2 frags).
// X tile lives in registers fp32 from load to store; LDS holds the bf16
// B-operand copy (Xl) + a fp32 transpose buffer (tmp).
// ---------------------------------------------------------------------------
__global__ __launch_bounds__(512, 4) void main_kernel(
    const float* __restrict__ img,        // [B,256,16384]
    const unsigned short* __restrict__ Wfrag,
    const float* __restrict__ cb,         // [256]
    const float* __restrict__ aw,         // attn_fc_w [256]
    const float* __restrict__ attn_b,     // [1]
    float* __restrict__ out)              // [B,256,16384]
{
    __shared__ unsigned short Xl[64 * 256];   // 32KB bf16 [s][c], 16B-block swizzled
    __shared__ float tmp[64 * 68];            // 17.4KB fp32 transpose buffer [c_local][s]
    __shared__ float partial[8][64];
    __shared__ float scl[64];

    const int t = threadIdx.x;
    const int l = t & 63;        // lane
    const int w = t >> 6;        // wave 0..7
    const int bid = blockIdx.x;
    const int b = bid >> 8;
    const int sb = (bid & 255) * STILE;
    const float* imgb = img + (size_t)b * CCH * SS;

    // ---- issue ALL global loads up front (16 KB of MLP per wave) ----------
    // thread t, iter it: idx = t + it*512; row c = idx>>4 (0..63 within chunk),
    // px = (t&15)*4. Coalesced float4.
    float4 xv[4][2];
#pragma unroll
    for (int cc = 0; cc < 4; ++cc)
#pragma unroll
        for (int it = 0; it < 2; ++it) {
            int idx = t + it * 512;
            xv[cc][it] = *reinterpret_cast<const float4*>(
                imgb + (size_t)(cc * 64 + (idx >> 4)) * SS + sb + (idx & 15) * 4);
        }

    // ---- stage X tile: regs -> tmp (fp32) -> Xl (bf16 [s][c] swizzled) ----
#pragma unroll
    for (int cc = 0; cc < 4; ++cc) {
#pragma unroll
        for (int it = 0; it < 2; ++it) {
            int idx = t + it * 512;
            *reinterpret_cast<float4*>(&tmp[(idx >> 4) * 68 + (idx & 15) * 4]) = xv[cc][it];
        }
        __syncthreads();
        {
            int s = l;
            int c0 = w * 8;                  // 8 channels per wave
            short8v pk;
#pragma unroll
            for (int j = 0; j < 8; ++j)
                pk[j] = (short)f2bf(tmp[(c0 + j) * 68 + s]);
            int cblk = cc * 8 + w;
            int idx2 = s * 256 + ((cblk ^ (s & 7)) << 3);
            *reinterpret_cast<short8v*>(&Xl[idx2]) = pk;
        }
        __syncthreads();
    }

    // ---- K loop: 8 steps of K=32, 8 MFMA per step per wave ----------------
    f32x4 acc[2][4];
#pragma unroll
    for (int m = 0; m < 2; ++m)
#pragma unroll
        for (int n = 0; n < 4; ++n)
            acc[m][n] = (f32x4){0.f, 0.f, 0.f, 0.f};

#pragma unroll
    for (int ks = 0; ks < 8; ++ks) {
        short8v a[2], bf[4];
#pragma unroll
        for (int m = 0; m < 2; ++m) {
            int ot = w * 2 + m;
            a[m] = *reinterpret_cast<const short8v*>(
                &Wfrag[(((ks * 16 + ot) * 64) + l) * 8]);
        }
#pragma unroll
        for (int n = 0; n < 4; ++n) {
            int s = n * 16 + (l & 15);
            int cblk = ks * 4 + (l >> 4);
            int idx = s * 256 + ((cblk ^ (s & 7)) << 3);
            bf[n] = *reinterpret_cast<const short8v*>(&Xl[idx]);
        }
#pragma unroll
        for (int m = 0; m < 2; ++m)
#pragma unroll
            for (int n = 0; n < 4; ++n)
                acc[m][n] = __builtin_amdgcn_mfma_f32_16x16x32_bf16(a[m], bf[n], acc[m][n], 0, 0, 0);
    }

    // ---- epilogue: score[s] = sigmoid(attn_b + sum_o aw[o]*tanh(T[o,s]+cb[o]))
    // D layout: col(=s within frag) = l&15, row(=o within frag) = (l>>4)*4 + r
    float p4[4];
#pragma unroll
    for (int n = 0; n < 4; ++n) {
        float accp = 0.f;
#pragma unroll
        for (int m = 0; m < 2; ++m)
#pragma unroll
            for (int r = 0; r < 4; ++r) {
                int o = (w * 2 + m) * 16 + ((l >> 4) << 2) + r;
                accp += aw[o] * tanh_fast(acc[m][n][r] + cb[o]);
            }
        accp += __shfl_xor(accp, 16);
        accp += __shfl_xor(accp, 32);
        p4[n] = accp;
    }
    if (l < 16) {
#pragma unroll
        for (int n = 0; n < 4; ++n) partial[w][n * 16 + l] = p4[n];
    }
    __syncthreads();
    if (t < 64) {
        float z = attn_b[0];
#pragma unroll
        for (int ww = 0; ww < 8; ++ww) z += partial[ww][t];
        scl[t] = 1.f / (1.f + __expf(-z));
    }
    __syncthreads();

    // ---- store from registers: out[b][r][sb + px..px+3] = xv * score ------
    float4 sc4 = *reinterpret_cast<const float4*>(&scl[(l & 15) * 4]);
#pragma unroll
    for (int cc = 0; cc < 4; ++cc)
#pragma unroll
        for (int it = 0; it < 2; ++it) {
            int idx = t + it * 512;
            int r = cc * 64 + (idx >> 4);
            float4 v = xv[cc][it];
            float4 o4;
            o4.x = v.x * sc4.x;
            o4.y = v.y * sc4.y;
            o4.z = v.z * sc4.z;
            o4.w = v.w * sc4.w;
            *reinterpret_cast<float4*>(
                out + (size_t)(b * CCH + r) * SS + sb + (l & 15) * 4) = o4;
        }
}

// ---------------------------------------------------------------------------
// Kernel 3: exact fp32 fixup for keypoint pixels (<=152). One block per (b,k).
// ---------------------------------------------------------------------------
__global__ __launch_bounds__(256) void fixup_kernel(
    const float* __restrict__ img,
    const float* __restrict__ img_fc_w,
    const float* __restrict__ aw,
    const float* __restrict__ attn_b,
    const float* __restrict__ cb,
    const float* __restrict__ delta,
    const int* __restrict__ pix,
    float* __restrict__ out)
{
    int bk = blockIdx.x;            // 0..151
    int b = bk / NK;
    int p = pix[bk];
    if (p < 0) return;              // uniform branch, before any barrier
    __shared__ float x[256];
    __shared__ float red[256];
    __shared__ float ssc;
    int t = threadIdx.x;
    const float* imgb = img + (size_t)b * CCH * SS;
    x[t] = imgb[(size_t)t * SS + p];
    __syncthreads();
    float dsum = 0.f;
    for (int k2 = 0; k2 < NK; ++k2)
        if (pix[b * NK + k2] == p) dsum += delta[t * NK + k2];
    float acc = cb[t] + dsum;
    for (int c = 0; c < CCH; ++c) acc += img_fc_w[t * CCH + c] * x[c];
    red[t] = aw[t] * tanh_fast(acc);
    __syncthreads();
    for (int off = 128; off > 0; off >>= 1) {
        if (t < off) red[t] += red[t + off];
        __syncthreads();
    }
    if (t == 0) ssc = 1.f / (1.f + __expf(-(red[0] + attn_b[0])));
    __syncthreads();
    out[(size_t)(b * CCH + t) * SS + p] = x[t] * ssc;
}

// ---------------------------------------------------------------------------
extern "C" void kernel_launch(void* const* d_in, const int* in_sizes, int n_in,
                              void* d_out, int out_size, void* d_ws, size_t ws_size,
                              hipStream_t stream) {
    (void)in_sizes; (void)n_in; (void)out_size; (void)ws_size;
    const float* img       = (const float*)d_in[0];
    const float* kf        = (const float*)d_in[1];
    const float* img_fc_w  = (const float*)d_in[2];
    const float* img_fc_b  = (const float*)d_in[3];
    const float* kp_proj_w = (const float*)d_in[4];
    const float* kp_proj_b = (const float*)d_in[5];
    const float* kp_fc_w   = (const float*)d_in[6];
    const float* kp_fc_b   = (const float*)d_in[7];
    const float* attn_fc_w = (const float*)d_in[8];
    const float* attn_fc_b = (const float*)d_in[9];
    float* out = (float*)d_out;

    char* ws = (char*)d_ws;
    float* cb             = (float*)(ws);            // 256 f  ->   1024 B
    float* delta          = (float*)(ws + 1024);     // 4864 f -> 19456 B
    int*   pix            = (int*)  (ws + 20480);    // 152 i  ->   608 B
    unsigned short* Wfrag = (unsigned short*)(ws + 21504); // 65536 u16 -> 131072 B

    precompute_kernel<<<1, 256, 0, stream>>>(kf, img_fc_w, img_fc_b, kp_proj_w,
                                             kp_proj_b, kp_fc_w, kp_fc_b,
                                             cb, delta, pix, Wfrag);
    main_kernel<<<NB * (SS / STILE), 512, 0, stream>>>(img, Wfrag, cb,
                                                       attn_fc_w, attn_fc_b, out);
    fixup_kernel<<<NB * NK, 256, 0, stream>>>(img, img_fc_w, attn_fc_w, attn_fc_b,
                                              cb, delta, pix, out);
}

// Round 3
// 92.975 us; speedup vs baseline: 1.0666x; 1.0666x over previous
//
#include <hip/hip_runtime.h>
#include <hip/hip_bf16.h>

#define CCH 256      // channels
#define HH 128
#define WW 128
#define SS (HH*WW)   // 16384 pixels per batch
#define NB 8         // batch
#define NK 19        // keypoints
#define STILE 64     // pixels per block

typedef __attribute__((ext_vector_type(8))) short short8v;   // 8 bf16 = 4 VGPR (MFMA operand)
typedef __attribute__((ext_vector_type(4))) float f32x4;     // MFMA accum

static __device__ __forceinline__ unsigned short f2bf(float x) {
    __hip_bfloat16 h = __float2bfloat16(x);
    return *reinterpret_cast<unsigned short*>(&h);
}
static __device__ __forceinline__ float bf2f(unsigned short u) {
    union { unsigned int i; float f; } z; z.i = ((unsigned int)u) << 16; return z.f;
}
static __device__ __forceinline__ float tanh_fast(float x) {
    // 1 - 2/(e^{2x}+1): monotone, no inf-inf, exact +/-1 saturation
    float e = __expf(2.f * x);
    return 1.f - 2.f / (e + 1.f);
}

// ---------------------------------------------------------------------------
// Kernel 1: precompute folded biases, delta weights, keypoint pixels, and
// img_fc_w rearranged to bf16 in MFMA A-fragment order:
//   Wfrag[((ks*16 + ot)*64 + lane)*8 + j] = bf16(W[ot*16 + (lane&15)][ks*32 + (lane>>4)*8 + j])
// ---------------------------------------------------------------------------
__global__ __launch_bounds__(256) void precompute_kernel(
    const float* __restrict__ kf,        // [B,K,3]
    const float* __restrict__ img_fc_w,  // [256,256]
    const float* __restrict__ img_fc_b,  // [256]
    const float* __restrict__ kp_proj_w, // [19,19]
    const float* __restrict__ kp_proj_b, // [19]
    const float* __restrict__ kp_fc_w,   // [256,19]
    const float* __restrict__ kp_fc_b,   // [256]
    float* __restrict__ cb,              // [256] combined bias
    float* __restrict__ delta,           // [256*19]
    int* __restrict__ pix,               // [B*K]
    unsigned short* __restrict__ Wfrag)  // [8*16*64*8]
{
    int t = threadIdx.x;
    {
        float acc = img_fc_b[t] + kp_fc_b[t];
        for (int k2 = 0; k2 < NK; ++k2) acc += kp_fc_w[t * NK + k2] * kp_proj_b[k2];
        cb[t] = acc;
        for (int k = 0; k < NK; ++k) {
            float d = 0.f;
            for (int k2 = 0; k2 < NK; ++k2) d += kp_fc_w[t * NK + k2] * kp_proj_w[k2 * NK + k];
            delta[t * NK + k] = d;
        }
    }
    if (t < NB * NK) {
        float kx = kf[t * 3 + 0], ky = kf[t * 3 + 1], vis = kf[t * 3 + 2];
        int p = -1;
        if (vis > 0.f) {
            int xi = (int)fminf(fmaxf(kx * (1.f / (float)WW), 0.f), (float)(WW - 1));
            int yi = (int)fminf(fmaxf(ky * (1.f / (float)HH), 0.f), (float)(HH - 1));
            p = yi * WW + xi;
        }
        pix[t] = p;
    }
    for (int g = t; g < 8 * 16 * 64; g += 256) {
        int lane = g & 63;
        int ot = (g >> 6) & 15;
        int ks = g >> 10;
        int o = ot * 16 + (lane & 15);
        int c0 = ks * 32 + (lane >> 4) * 8;
#pragma unroll
        for (int j = 0; j < 8; ++j)
            Wfrag[g * 8 + j] = f2bf(img_fc_w[o * CCH + c0 + j]);
    }
}

// ---------------------------------------------------------------------------
// Kernel 2: main fused GEMM + epilogue. Block = 512 thr (8 waves).
// Tile: 256 o x 64 s. Wave w owns o in [w*32, w*32+32)  (m = 2 frags).
// Staging: each thread owns (s = t&63, 32 channels c0 = (t>>6)*32). Loads are
// 32 independent scalar dwords (coalesced 256B per inst across lanes), cvt to
// bf16, written DIRECTLY into the swizzled [s][c] MFMA-B layout with 4
// ds_write_b128. One barrier total for staging (was 8).
// ---------------------------------------------------------------------------
__global__ __launch_bounds__(512, 4) void main_kernel(
    const float* __restrict__ img,        // [B,256,16384]
    const unsigned short* __restrict__ Wfrag,
    const float* __restrict__ cb,         // [256]
    const float* __restrict__ aw,         // attn_fc_w [256]
    const float* __restrict__ attn_b,     // [1]
    float* __restrict__ out)              // [B,256,16384]
{
    __shared__ unsigned short Xl[64 * 256];   // 32KB bf16 [s][c], 16B-block swizzled
    __shared__ float partial[8][64];
    __shared__ float scl[64];

    const int t = threadIdx.x;
    const int l = t & 63;        // lane
    const int w = t >> 6;        // wave 0..7
    const int bid = blockIdx.x;
    const int b = bid >> 8;
    const int sb = (bid & 255) * STILE;
    const float* imgb = img + (size_t)b * CCH * SS;

    const int sl = t & 63;            // pixel-in-tile this thread owns
    const int c0 = (t >> 6) * 32;     // 32 channels this thread owns

    // ---- stage: 32 independent scalar loads -> bf16 -> swizzled LDS -------
    {
        float xf[32];
#pragma unroll
        for (int j = 0; j < 32; ++j)
            xf[j] = imgb[(size_t)(c0 + j) * SS + sb + sl];
#pragma unroll
        for (int jb = 0; jb < 4; ++jb) {
            short8v pk;
#pragma unroll
            for (int e = 0; e < 8; ++e) pk[e] = (short)f2bf(xf[jb * 8 + e]);
            int cblk = (c0 >> 3) + jb;
            int idx = sl * 256 + ((cblk ^ (sl & 7)) << 3);
            *reinterpret_cast<short8v*>(&Xl[idx]) = pk;
        }
    }
    __syncthreads();

    // ---- K loop: 8 steps of K=32, 8 MFMA per step per wave ----------------
    f32x4 acc[2][4];
#pragma unroll
    for (int m = 0; m < 2; ++m)
#pragma unroll
        for (int n = 0; n < 4; ++n)
            acc[m][n] = (f32x4){0.f, 0.f, 0.f, 0.f};

#pragma unroll
    for (int ks = 0; ks < 8; ++ks) {
        short8v a[2], bf[4];
#pragma unroll
        for (int m = 0; m < 2; ++m) {
            int ot = w * 2 + m;
            a[m] = *reinterpret_cast<const short8v*>(
                &Wfrag[(((ks * 16 + ot) * 64) + l) * 8]);
        }
#pragma unroll
        for (int n = 0; n < 4; ++n) {
            int s = n * 16 + (l & 15);
            int cblk = ks * 4 + (l >> 4);
            int idx = s * 256 + ((cblk ^ (s & 7)) << 3);
            bf[n] = *reinterpret_cast<const short8v*>(&Xl[idx]);
        }
#pragma unroll
        for (int m = 0; m < 2; ++m)
#pragma unroll
            for (int n = 0; n < 4; ++n)
                acc[m][n] = __builtin_amdgcn_mfma_f32_16x16x32_bf16(a[m], bf[n], acc[m][n], 0, 0, 0);
    }

    // ---- epilogue: score[s] = sigmoid(attn_b + sum_o aw[o]*tanh(T[o,s]+cb[o]))
    // D layout: col(=s within frag) = l&15, row(=o within frag) = (l>>4)*4 + r
    float p4[4];
#pragma unroll
    for (int n = 0; n < 4; ++n) {
        float accp = 0.f;
#pragma unroll
        for (int m = 0; m < 2; ++m)
#pragma unroll
            for (int r = 0; r < 4; ++r) {
                int o = (w * 2 + m) * 16 + ((l >> 4) << 2) + r;
                accp += aw[o] * tanh_fast(acc[m][n][r] + cb[o]);
            }
        accp += __shfl_xor(accp, 16);
        accp += __shfl_xor(accp, 32);
        p4[n] = accp;
    }
    if (l < 16) {
#pragma unroll
        for (int n = 0; n < 4; ++n) partial[w][n * 16 + l] = p4[n];
    }
    __syncthreads();
    if (t < 64) {
        float z = attn_b[0];
#pragma unroll
        for (int ww = 0; ww < 8; ++ww) z += partial[ww][t];
        scl[t] = 1.f / (1.f + __expf(-z));
    }
    __syncthreads();

    // ---- store: thread re-reads its own 32 bf16 channels, scales, writes --
    {
        float sc = scl[sl];
#pragma unroll
        for (int jb = 0; jb < 4; ++jb) {
            int cblk = (c0 >> 3) + jb;
            int idx = sl * 256 + ((cblk ^ (sl & 7)) << 3);
            short8v v = *reinterpret_cast<const short8v*>(&Xl[idx]);
#pragma unroll
            for (int e = 0; e < 8; ++e)
                out[(size_t)(b * CCH + c0 + jb * 8 + e) * SS + sb + sl] =
                    bf2f((unsigned short)v[e]) * sc;
        }
    }
}

// ---------------------------------------------------------------------------
// Kernel 3: exact fp32 fixup for keypoint pixels (<=152). One block per (b,k).
// ---------------------------------------------------------------------------
__global__ __launch_bounds__(256) void fixup_kernel(
    const float* __restrict__ img,
    const float* __restrict__ img_fc_w,
    const float* __restrict__ aw,
    const float* __restrict__ attn_b,
    const float* __restrict__ cb,
    const float* __restrict__ delta,
    const int* __restrict__ pix,
    float* __restrict__ out)
{
    int bk = blockIdx.x;            // 0..151
    int b = bk / NK;
    int p = pix[bk];
    if (p < 0) return;              // uniform branch, before any barrier
    __shared__ float x[256];
    __shared__ float red[256];
    __shared__ float ssc;
    int t = threadIdx.x;
    const float* imgb = img + (size_t)b * CCH * SS;
    x[t] = imgb[(size_t)t * SS + p];
    __syncthreads();
    float dsum = 0.f;
    for (int k2 = 0; k2 < NK; ++k2)
        if (pix[b * NK + k2] == p) dsum += delta[t * NK + k2];
    float acc = cb[t] + dsum;
    for (int c = 0; c < CCH; ++c) acc += img_fc_w[t * CCH + c] * x[c];
    red[t] = aw[t] * tanh_fast(acc);
    __syncthreads();
    for (int off = 128; off > 0; off >>= 1) {
        if (t < off) red[t] += red[t + off];
        __syncthreads();
    }
    if (t == 0) ssc = 1.f / (1.f + __expf(-(red[0] + attn_b[0])));
    __syncthreads();
    out[(size_t)(b * CCH + t) * SS + p] = x[t] * ssc;
}

// ---------------------------------------------------------------------------
extern "C" void kernel_launch(void* const* d_in, const int* in_sizes, int n_in,
                              void* d_out, int out_size, void* d_ws, size_t ws_size,
                              hipStream_t stream) {
    (void)in_sizes; (void)n_in; (void)out_size; (void)ws_size;
    const float* img       = (const float*)d_in[0];
    const float* kf        = (const float*)d_in[1];
    const float* img_fc_w  = (const float*)d_in[2];
    const float* img_fc_b  = (const float*)d_in[3];
    const float* kp_proj_w = (const float*)d_in[4];
    const float* kp_proj_b = (const float*)d_in[5];
    const float* kp_fc_w   = (const float*)d_in[6];
    const float* kp_fc_b   = (const float*)d_in[7];
    const float* attn_fc_w = (const float*)d_in[8];
    const float* attn_fc_b = (const float*)d_in[9];
    float* out = (float*)d_out;

    char* ws = (char*)d_ws;
    float* cb             = (float*)(ws);            // 256 f  ->   1024 B
    float* delta          = (float*)(ws + 1024);     // 4864 f -> 19456 B
    int*   pix            = (int*)  (ws + 20480);    // 152 i  ->   608 B
    unsigned short* Wfrag = (unsigned short*)(ws + 21504); // 65536 u16 -> 131072 B

    precompute_kernel<<<1, 256, 0, stream>>>(kf, img_fc_w, img_fc_b, kp_proj_w,
                                             kp_proj_b, kp_fc_w, kp_fc_b,
                                             cb, delta, pix, Wfrag);
    main_kernel<<<NB * (SS / STILE), 512, 0, stream>>>(img, Wfrag, cb,
                                                       attn_fc_w, attn_fc_b, out);
    fixup_kernel<<<NB * NK, 256, 0, stream>>>(img, img_fc_w, attn_fc_w, attn_fc_b,
                                              cb, delta, pix, out);
}